// Round 5
// baseline (56.777 us; speedup 1.0000x reference)
//
#include <hip/hip_runtime.h>

typedef float v4f __attribute__((ext_vector_type(4)));

#define WDIM 512
#define HDIM 512
#define NEG_INF (-__builtin_inff())
#define THRESH 0.3f
#define INV512 0.001953125f   // 1/512 exact; x*INV512 == x/512 bit-exact (pow2)

// One thread computes 4 contiguous pixels (last axis). Block = 512 threads
// = 4 rows (bounds hm halo HBM refetch at 1.5x independent of L2 timing).
// Grid = 32 images * 128 blocks = 4096. Halo columns via shfl; out5 staged
// through flat LDS (b128 both sides, 2-way banks = free) then stored
// coalesced + nontemporal; sizes loaded nontemporal; hm cached for halo reuse.
__global__ __launch_bounds__(512) void ToBoxes_52158082843018_kernel(
    const float* __restrict__ hm, const float* __restrict__ sz,
    float* __restrict__ kp_out, float* __restrict__ out5)
{
    __shared__ float lds[10240];   // 4 rows * 512 px * 5 ch, flat

    // XCD-contiguous remap: blocks [x*512,(x+1)*512) -> XCD x. 4096 % 8 == 0.
    const int orig = blockIdx.x;
    const int blk  = (orig & 7) * 512 + (orig >> 3);

    const int b    = blk >> 7;       // 128 blocks per image
    const int ir   = blk & 127;      // 4 rows per block
    const int tid  = threadIdx.x;
    const int lane = tid & 63;
    const int i = ir * 4 + (tid >> 7);     // row (W axis)
    const int j = (tid & 127) << 2;        // col (H axis), multiple of 4

    // read-once NT sizes loads first (longest latency path)
    const float* szb = sz + (size_t)b * 2 * WDIM * HDIM + (size_t)i * HDIM;
    v4f wv = __builtin_nontemporal_load(reinterpret_cast<const v4f*>(szb + j));
    v4f hv = __builtin_nontemporal_load(
        reinterpret_cast<const v4f*>(szb + (size_t)WDIM * HDIM + j));

    const float* row = hm + ((size_t)b * WDIM + i) * HDIM;

    float c[6], u[6], d[6];

    // 6 halo-extended columns of one row: vector load + lane shuffles;
    // only lanes 0/63 do a predicated 1-lane edge load.
    auto load_row6 = [&](const float* rp, float* dst) {
        float4 v = *reinterpret_cast<const float4*>(rp + j);
        dst[1] = v.x; dst[2] = v.y; dst[3] = v.z; dst[4] = v.w;
        float lft = __shfl_up(v.w, 1);
        float rgt = __shfl_down(v.x, 1);
        if (lane == 0)  lft = (j > 0)        ? rp[j - 1] : NEG_INF;
        if (lane == 63) rgt = (j + 4 < HDIM) ? rp[j + 4] : NEG_INF;
        dst[0] = lft; dst[5] = rgt;
    };

    load_row6(row, c);
    if (i > 0) {                      // wave-uniform (i uniform within wave)
        load_row6(row - HDIM, u);
    } else {
        #pragma unroll
        for (int k = 0; k < 6; ++k) u[k] = NEG_INF;
    }
    if (i < WDIM - 1) {
        load_row6(row + HDIM, d);
    } else {
        #pragma unroll
        for (int k = 0; k < 6; ++k) d[k] = NEG_INF;
    }

    const float wsz[4] = { wv.x, wv.y, wv.z, wv.w };
    const float hsz[4] = { hv.x, hv.y, hv.z, hv.w };
    const float cxv = (float)i * INV512;

    float kpv[4];
    float o[20];
    #pragma unroll
    for (int k = 0; k < 4; ++k) {
        const float v = c[k + 1];
        float m = fmaxf(u[k], u[k + 1]);
        m = fmaxf(m, u[k + 2]);
        m = fmaxf(m, c[k]);
        m = fmaxf(m, c[k + 1]);
        m = fmaxf(m, c[k + 2]);
        m = fmaxf(m, d[k]);
        m = fmaxf(m, d[k + 1]);
        m = fmaxf(m, d[k + 2]);
        const bool keep = (m == v) && (v > THRESH);
        kpv[k] = keep ? 1.0f : 0.0f;
        const float cyv = (float)(j + k) * INV512;
        o[k * 5 + 0] = keep ? v      : 0.0f;
        o[k * 5 + 1] = keep ? cxv    : 0.0f;
        o[k * 5 + 2] = keep ? cyv    : 0.0f;
        o[k * 5 + 3] = keep ? wsz[k] : 0.0f;
        o[k * 5 + 4] = keep ? hsz[k] : 0.0f;
    }

    // kp: coalesced, write-once -> nontemporal
    const size_t pix = ((size_t)b * WDIM + i) * HDIM + j;
    v4f kv = { kpv[0], kpv[1], kpv[2], kpv[3] };
    __builtin_nontemporal_store(kv, reinterpret_cast<v4f*>(kp_out + pix));

    // stage out5 flat in LDS: thread t owns floats [20t, 20t+20)
    #pragma unroll
    for (int q = 0; q < 5; ++q) {
        v4f t = { o[4 * q], o[4 * q + 1], o[4 * q + 2], o[4 * q + 3] };
        *reinterpret_cast<v4f*>(&lds[tid * 20 + q * 4]) = t;
    }
    __syncthreads();

    // block's out5 region: 4 rows * 512 px * 5 ch = 10240 contiguous floats
    float* op = out5 + ((size_t)b * WDIM + (size_t)(ir * 4)) * HDIM * 5;
    #pragma unroll
    for (int k = 0; k < 5; ++k) {
        const int m = k * 2048 + (tid << 2);
        v4f vv = *reinterpret_cast<const v4f*>(&lds[m]);
        __builtin_nontemporal_store(vv, reinterpret_cast<v4f*>(op + m));
    }
}

extern "C" void kernel_launch(void* const* d_in, const int* in_sizes, int n_in,
                              void* d_out, int out_size, void* d_ws, size_t ws_size,
                              hipStream_t stream) {
    const float* hm = (const float*)d_in[0];   // (32,1,512,512)
    const float* sz = (const float*)d_in[1];   // (32,2,512,512)
    float* out  = (float*)d_out;
    float* kp   = out;                                   // (32,512,512) as 0/1
    float* out5 = out + (size_t)32 * 512 * 512;          // (32,512,512,5)

    const int blocks = 32 * 128;   // 4 rows per block
    ToBoxes_52158082843018_kernel<<<blocks, 512, 0, stream>>>(hm, sz, kp, out5);
}